// Round 2
// baseline (6683.176 us; speedup 1.0000x reference)
//
#include <hip/hip_runtime.h>
#include <hip/hip_bf16.h>

// ---------------------------------------------------------------------------
// GRU with per-timestep BatchNorm on the input projections.
//   T=512, B=64, I=H=512.
// Round 1 fix: BN stats must span the FULL batch (64 rows). Round 0 reduced
// over 16 rows (one wave) only. BN is now computed exactly in proj_gemm's
// epilogue (tile == one timestep x full batch x 64 cols, fp32 accumulators,
// cross-wave LDS reduce) and stored as fp16 "BN(u) + W_bias"; the scan just
// adds it. U biases dropped (BN(y+c)==BN(y)); W biases folded into stored u.
// ---------------------------------------------------------------------------

using bf16x8 = __attribute__((ext_vector_type(8))) short;
using f32x4  = __attribute__((ext_vector_type(4))) float;
using fvec4  = __attribute__((ext_vector_type(4))) float;

#define NWG 32

static __device__ __forceinline__ unsigned short f2bf(float f) {
  union { float ff; unsigned int i; } v; v.ff = f;
  unsigned int x = v.i;
  x += 0x7fffu + ((x >> 16) & 1u);   // RNE
  return (unsigned short)(x >> 16);
}
static __device__ __forceinline__ float h2f(unsigned short u) {
  union { unsigned short s; _Float16 h; } v; v.s = u; return (float)v.h;
}
static __device__ __forceinline__ unsigned short f2h(float f) {
  union { unsigned short s; _Float16 h; } v; v.h = (_Float16)f; return v.s;
}
static __device__ __forceinline__ float sigmoidf_(float x) {
  return 1.0f / (1.0f + __expf(-x));
}
static __device__ __forceinline__ float tanhf_(float x) {
  return 2.0f / (1.0f + __expf(-2.0f * x)) - 1.0f;
}

// ---------------- phase 1: ub_m = BN(x @ U_m^T) + W_m_b  (fp16 out) --------
// 64x64 tile = one timestep x batch(64) x 64 cols. BK=64, 4 waves,
// mfma_f32_16x16x32_bf16. BN stats from fp32 accs: shfl over kseg (16 rows)
// then LDS over the 4 waves (64 rows).
__global__ __launch_bounds__(256) void proj_gemm(
    const float* __restrict__ x,
    const float* __restrict__ Uz, const float* __restrict__ Ur,
    const float* __restrict__ Uh,
    const float* __restrict__ Wzb, const float* __restrict__ Wrb,
    const float* __restrict__ Whb,
    const float* __restrict__ gamma, const float* __restrict__ beta,
    unsigned short* __restrict__ ubz, unsigned short* __restrict__ ubr,
    unsigned short* __restrict__ ubh)
{
  const int mt = blockIdx.x, nt = blockIdx.y, mat = blockIdx.z;
  const float* U  = (mat == 0) ? Uz  : (mat == 1 ? Ur  : Uh);
  const float* Wb = (mat == 0) ? Wzb : (mat == 1 ? Wrb : Whb);
  unsigned short* uo = (mat == 0) ? ubz : (mat == 1 ? ubr : ubh);

  __shared__ short lA[4096];   // [64][64] bf16, 128B rows, XOR-swizzled
  __shared__ short lB[4096];

  const int tid = threadIdx.x;
  const int wave = tid >> 6, lane = tid & 63;
  const int fl = lane & 15, kseg = lane >> 4;

  f32x4 acc[4];
  #pragma unroll
  for (int n = 0; n < 4; ++n) acc[n] = f32x4{0.f, 0.f, 0.f, 0.f};

  const float* xb = x + (size_t)mt * 64 * 512;
  const float* Ub = U + (size_t)nt * 64 * 512;

  for (int kt = 0; kt < 8; ++kt) {
    __syncthreads();
    #pragma unroll
    for (int c = 0; c < 2; ++c) {
      const int chunk = tid + 256 * c;       // 0..511
      const int row = chunk >> 3, kc = chunk & 7;
      const int lb = row * 128 + ((kc * 16) ^ ((row & 7) << 4));
      {
        const float* g = xb + (size_t)row * 512 + kt * 64 + kc * 8;
        fvec4 a0 = *(const fvec4*)g, a1 = *(const fvec4*)(g + 4);
        bf16x8 p;
        p[0] = (short)f2bf(a0[0]); p[1] = (short)f2bf(a0[1]);
        p[2] = (short)f2bf(a0[2]); p[3] = (short)f2bf(a0[3]);
        p[4] = (short)f2bf(a1[0]); p[5] = (short)f2bf(a1[1]);
        p[6] = (short)f2bf(a1[2]); p[7] = (short)f2bf(a1[3]);
        *(bf16x8*)((char*)lA + lb) = p;
      }
      {
        const float* g = Ub + (size_t)row * 512 + kt * 64 + kc * 8;
        fvec4 a0 = *(const fvec4*)g, a1 = *(const fvec4*)(g + 4);
        bf16x8 p;
        p[0] = (short)f2bf(a0[0]); p[1] = (short)f2bf(a0[1]);
        p[2] = (short)f2bf(a0[2]); p[3] = (short)f2bf(a0[3]);
        p[4] = (short)f2bf(a1[0]); p[5] = (short)f2bf(a1[1]);
        p[6] = (short)f2bf(a1[2]); p[7] = (short)f2bf(a1[3]);
        *(bf16x8*)((char*)lB + lb) = p;
      }
    }
    __syncthreads();
    #pragma unroll
    for (int kk = 0; kk < 2; ++kk) {
      const int ar = wave * 16 + fl;
      bf16x8 af = *(const bf16x8*)((char*)lA + ar * 128 +
                    ((kk * 64 + kseg * 16) ^ ((ar & 7) << 4)));
      #pragma unroll
      for (int n = 0; n < 4; ++n) {
        const int br = n * 16 + fl;
        bf16x8 bfr = *(const bf16x8*)((char*)lB + br * 128 +
                      ((kk * 64 + kseg * 16) ^ ((br & 7) << 4)));
        acc[n] = __builtin_amdgcn_mfma_f32_16x16x32_bf16(af, bfr, acc[n], 0, 0, 0);
      }
    }
  }

  // ---- BN epilogue: exact batch stats (all 64 rows), from fp32 accs ----
  float sn[4], qn[4];
  #pragma unroll
  for (int n = 0; n < 4; ++n) {
    sn[n] = acc[n][0] + acc[n][1] + acc[n][2] + acc[n][3];
    qn[n] = acc[n][0]*acc[n][0] + acc[n][1]*acc[n][1]
          + acc[n][2]*acc[n][2] + acc[n][3]*acc[n][3];
    sn[n] += __shfl_xor(sn[n], 16); qn[n] += __shfl_xor(qn[n], 16);
    sn[n] += __shfl_xor(sn[n], 32); qn[n] += __shfl_xor(qn[n], 32);
  }
  __syncthreads();                       // all MFMA LDS reads done; reuse lA/lB
  float* sArr = (float*)lA;              // [wave*64 + n*16 + fl]
  float* qArr = (float*)lB;
  if (kseg == 0) {
    #pragma unroll
    for (int n = 0; n < 4; ++n) {
      sArr[wave * 64 + n * 16 + fl] = sn[n];
      qArr[wave * 64 + n * 16 + fl] = qn[n];
    }
  }
  __syncthreads();

  const int c0 = nt * 64;
  const int r0 = mt * 64 + wave * 16 + kseg * 4;   // global row (t*64 + b)
  #pragma unroll
  for (int n = 0; n < 4; ++n) {
    const int idx = n * 16 + fl;
    const float s = sArr[idx] + sArr[64+idx] + sArr[128+idx] + sArr[192+idx];
    const float q = qArr[idx] + qArr[64+idx] + qArr[128+idx] + qArr[192+idx];
    const float mu = s * 0.015625f;
    const float rs = rsqrtf(q * 0.015625f - mu * mu + 1e-5f);
    const int col = c0 + idx;
    const float gb  = gamma[col] * rs;
    const float ofs = beta[col] + Wb[col] - gb * mu;   // fold W bias here
    #pragma unroll
    for (int i = 0; i < 4; ++i)
      uo[(size_t)(r0 + i) * 512 + col] = f2h(gb * acc[n][i] + ofs);
  }
}

// ---------------- phase 2: persistent GRU scan ----------------
__global__ __launch_bounds__(256) void gru_scan(
    const float* __restrict__ h0,
    const float* __restrict__ Wz, const float* __restrict__ Wr,
    const float* __restrict__ Wh,
    const unsigned short* __restrict__ ubz, const unsigned short* __restrict__ ubr,
    const unsigned short* __restrict__ ubh,
    unsigned short* __restrict__ hbuf, unsigned short* __restrict__ rhbuf,
    unsigned int* __restrict__ bars, float* __restrict__ out)
{
  const int wg = blockIdx.x;           // owns cols [wg*16, wg*16+16)
  const int tid = threadIdx.x;
  const int wave = tid >> 6, lane = tid & 63;
  const int fl = lane & 15, kseg = lane >> 4;
  const int col = wg * 16 + fl;        // this lane's output column
  const int row0 = wave * 16 + kseg * 4;   // first of 4 C-rows (batch)
  const int hrow = wave * 16 + fl;         // A-frag row (batch)

  // W slices, bf16, [mat][16 rows][512 k], 1KB rows, XOR-swizzled
  __shared__ short lW[24576];

  for (int c = tid; c < 3072; c += 256) {        // 8-elem chunks
    const int m = c >> 10, rem = c & 1023;
    const int r = rem >> 6, kc = rem & 63;
    const float* W = (m == 0) ? Wz : (m == 1 ? Wr : Wh);
    const float* g = W + (size_t)(wg * 16 + r) * 512 + kc * 8;
    bf16x8 p;
    #pragma unroll
    for (int j = 0; j < 8; ++j) p[j] = (short)f2bf(g[j]);
    *(bf16x8*)((char*)lW + m * 16384 + r * 1024 + ((kc * 16) ^ ((r & 7) << 4))) = p;
  }

  // own h columns, fp32, never leave registers
  float hown[4];
  #pragma unroll
  for (int i = 0; i < 4; ++i) {
    const float v = h0[(size_t)(row0 + i) * 512 + col];
    hown[i] = v;
    hbuf[(size_t)(row0 + i) * 512 + col] = f2bf(v);
  }
  __syncthreads();
  if (tid == 0)
    __hip_atomic_fetch_add(&bars[0], 1u, __ATOMIC_RELEASE, __HIP_MEMORY_SCOPE_AGENT);

  // prefetch BN-ed u for t=0 (biases folded in already)
  float uzv[4], urv[4], uhv[4];
  #pragma unroll
  for (int i = 0; i < 4; ++i) {
    const size_t o = (size_t)(row0 + i) * 512 + col;
    uzv[i] = h2f(ubz[o]); urv[i] = h2f(ubr[o]); uhv[i] = h2f(ubh[o]);
  }

  for (int t = 0; t < 512; ++t) {
    // ---- wait: h (version t) visible everywhere
    if ((tid & 63) == 0) {
      while (__hip_atomic_load(&bars[2 * t], __ATOMIC_RELAXED,
                               __HIP_MEMORY_SCOPE_AGENT) < NWG)
        __builtin_amdgcn_s_sleep(1);
    }
    __builtin_amdgcn_fence(__ATOMIC_ACQUIRE, "agent");
    __syncthreads();

    // ---- phase 1: z, r gates for our 16 columns
    bf16x8 af[16];
    #pragma unroll
    for (int kk = 0; kk < 16; ++kk)
      af[kk] = *(const bf16x8*)((const char*)hbuf + hrow * 1024 + kk * 64 + kseg * 16);

    f32x4 zacc = f32x4{0.f,0.f,0.f,0.f}, racc = f32x4{0.f,0.f,0.f,0.f};
    #pragma unroll
    for (int kk = 0; kk < 16; ++kk) {
      const int wof = (kk * 64 + kseg * 16) ^ ((fl & 7) << 4);
      bf16x8 b0 = *(const bf16x8*)((const char*)lW + fl * 1024 + wof);
      bf16x8 b1 = *(const bf16x8*)((const char*)lW + 16384 + fl * 1024 + wof);
      zacc = __builtin_amdgcn_mfma_f32_16x16x32_bf16(af[kk], b0, zacc, 0, 0, 0);
      racc = __builtin_amdgcn_mfma_f32_16x16x32_bf16(af[kk], b1, racc, 0, 0, 0);
    }

    float z4[4], r4[4];
    #pragma unroll
    for (int i = 0; i < 4; ++i) {
      z4[i] = sigmoidf_(zacc[i] + uzv[i]);
      r4[i] = sigmoidf_(racc[i] + urv[i]);
    }

    // rh slice (own cols, fp32 h from regs)
    #pragma unroll
    for (int i = 0; i < 4; ++i)
      rhbuf[(size_t)(row0 + i) * 512 + col] = f2bf(r4[i] * hown[i]);

    // ---- mid barrier: rh complete
    __syncthreads();
    if (tid == 0)
      __hip_atomic_fetch_add(&bars[2*t+1], 1u, __ATOMIC_RELEASE, __HIP_MEMORY_SCOPE_AGENT);
    if ((tid & 63) == 0) {
      while (__hip_atomic_load(&bars[2*t+1], __ATOMIC_RELAXED,
                               __HIP_MEMORY_SCOPE_AGENT) < NWG)
        __builtin_amdgcn_s_sleep(1);
    }
    __builtin_amdgcn_fence(__ATOMIC_ACQUIRE, "agent");
    __syncthreads();

    // ---- phase 2: candidate state
    #pragma unroll
    for (int kk = 0; kk < 16; ++kk)
      af[kk] = *(const bf16x8*)((const char*)rhbuf + hrow * 1024 + kk * 64 + kseg * 16);

    f32x4 hacc = f32x4{0.f,0.f,0.f,0.f};
    #pragma unroll
    for (int kk = 0; kk < 16; ++kk) {
      const int wof = (kk * 64 + kseg * 16) ^ ((fl & 7) << 4);
      bf16x8 b2 = *(const bf16x8*)((const char*)lW + 32768 + fl * 1024 + wof);
      hacc = __builtin_amdgcn_mfma_f32_16x16x32_bf16(af[kk], b2, hacc, 0, 0, 0);
    }

    float hn[4];
    #pragma unroll
    for (int i = 0; i < 4; ++i) {
      const float nb = tanhf_(hacc[i] + uhv[i]);
      hn[i] = (1.f - z4[i]) * hown[i] + z4[i] * nb;
      hown[i] = hn[i];
    }
    #pragma unroll
    for (int i = 0; i < 4; ++i)
      hbuf[(size_t)(row0 + i) * 512 + col] = f2bf(hn[i]);

    // ---- end barrier: h (version t+1) complete
    __syncthreads();
    if (tid == 0)
      __hip_atomic_fetch_add(&bars[2*t+2], 1u, __ATOMIC_RELEASE, __HIP_MEMORY_SCOPE_AGENT);

    // prefetch next step's u during the (upcoming) barrier wait
    if (t + 1 < 512) {
      const size_t tb = (size_t)(t + 1) * 64 * 512;
      #pragma unroll
      for (int i = 0; i < 4; ++i) {
        const size_t o = tb + (size_t)(row0 + i) * 512 + col;
        uzv[i] = h2f(ubz[o]); urv[i] = h2f(ubr[o]); uhv[i] = h2f(ubh[o]);
      }
    }
    // outputs (fire-and-forget, after arrival): both copies are hs[t]
    {
      const size_t tb = (size_t)t * 64 * 512;
      #pragma unroll
      for (int i = 0; i < 4; ++i) {
        const size_t o = tb + (size_t)(row0 + i) * 512 + col;
        const float v = hn[i];
        out[o] = v;
        out[16777216 + o] = v;
      }
    }
  }
}

extern "C" void kernel_launch(void* const* d_in, const int* in_sizes, int n_in,
                              void* d_out, int out_size, void* d_ws, size_t ws_size,
                              hipStream_t stream) {
  (void)in_sizes; (void)n_in; (void)out_size; (void)ws_size;
  const float* x   = (const float*)d_in[0];
  const float* h0  = (const float*)d_in[1];
  const float* Wz  = (const float*)d_in[2];
  const float* Wzb = (const float*)d_in[3];
  const float* Uz  = (const float*)d_in[4];
  const float* Wr  = (const float*)d_in[6];
  const float* Wrb = (const float*)d_in[7];
  const float* Ur  = (const float*)d_in[8];
  const float* Wh  = (const float*)d_in[10];
  const float* Whb = (const float*)d_in[11];
  const float* Uh  = (const float*)d_in[12];
  const float* gam = (const float*)d_in[14];
  const float* bet = (const float*)d_in[15];
  float* out = (float*)d_out;

  char* ws = (char*)d_ws;
  // layout: [0,8KB) barrier counters | hbuf 64KB | rhbuf 64KB |
  //         [256KB) ub_z, ub_r, ub_h (fp16 BN-ed + bias, 32MB each)
  unsigned int*   bars  = (unsigned int*)(ws);
  unsigned short* hbuf  = (unsigned short*)(ws + 8192);
  unsigned short* rhbuf = (unsigned short*)(ws + 8192 + 65536);
  unsigned short* uzb   = (unsigned short*)(ws + 262144);
  unsigned short* urb   = (unsigned short*)(ws + 262144 + 33554432);
  unsigned short* uhb   = (unsigned short*)(ws + 262144 + 2ll * 33554432);

  hipMemsetAsync(bars, 0, 8192, stream);   // 1025 barrier counters -> 0

  dim3 gp(512, 8, 3);
  proj_gemm<<<gp, 256, 0, stream>>>(x, Uz, Ur, Uh, Wzb, Wrb, Whb,
                                    gam, bet, uzb, urb, uhb);
  gru_scan<<<dim3(NWG), 256, 0, stream>>>(h0, Wz, Wr, Wh, uzb, urb, uhb,
                                          hbuf, rhbuf, bars, out);
}

// Round 3
// 5738.538 us; speedup vs baseline: 1.1646x; 1.1646x over previous
//
#include <hip/hip_runtime.h>
#include <hip/hip_bf16.h>

// ---------------------------------------------------------------------------
// GRU with per-timestep BatchNorm on the input projections.
//   T=512, B=64, I=H=512.
// Round 2 -> 3: the scan was barrier-bound (~5us per inter-WG barrier) due to
// single-line atomic contention (32 fetch_adds + 32 pollers on ONE cache
// line). New barrier: per-WG epoch flag on its own 128B line; arrival is a
// single release-store (no RMW), waiters poll all 32 flags with 32 parallel
// lanes (every wave polls; no post-wait __syncthreads). Epochs are monotonic
// so flags never reset (no ABA). Also: BN-ed u stored transposed
// [t][col][batch] so scan prefetch is 3 x 8B vector loads.
// ---------------------------------------------------------------------------

using bf16x8 = __attribute__((ext_vector_type(8))) short;
using f32x4  = __attribute__((ext_vector_type(4))) float;
using fvec4  = __attribute__((ext_vector_type(4))) float;
using s16x4  = __attribute__((ext_vector_type(4))) short;

#define NWG 32

static __device__ __forceinline__ unsigned short f2bf(float f) {
  union { float ff; unsigned int i; } v; v.ff = f;
  unsigned int x = v.i;
  x += 0x7fffu + ((x >> 16) & 1u);   // RNE
  return (unsigned short)(x >> 16);
}
static __device__ __forceinline__ float h2f(unsigned short u) {
  union { unsigned short s; _Float16 h; } v; v.s = u; return (float)v.h;
}
static __device__ __forceinline__ unsigned short f2h(float f) {
  union { unsigned short s; _Float16 h; } v; v.h = (_Float16)f; return v.s;
}
static __device__ __forceinline__ float sigmoidf_(float x) {
  return 1.0f / (1.0f + __expf(-x));
}
static __device__ __forceinline__ float tanhf_(float x) {
  return 2.0f / (1.0f + __expf(-2.0f * x)) - 1.0f;
}

// ---------------- phase 1: ub_m = BN(x @ U_m^T) + W_m_b  (fp16 out) --------
// 64x64 tile = one timestep x batch(64) x 64 cols. BK=64, 4 waves,
// mfma_f32_16x16x32_bf16. BN stats from fp32 accs: shfl over kseg (16 rows)
// then LDS over the 4 waves (64 rows). Output layout [t][col][batch].
__global__ __launch_bounds__(256) void proj_gemm(
    const float* __restrict__ x,
    const float* __restrict__ Uz, const float* __restrict__ Ur,
    const float* __restrict__ Uh,
    const float* __restrict__ Wzb, const float* __restrict__ Wrb,
    const float* __restrict__ Whb,
    const float* __restrict__ gamma, const float* __restrict__ beta,
    unsigned short* __restrict__ ubz, unsigned short* __restrict__ ubr,
    unsigned short* __restrict__ ubh)
{
  const int mt = blockIdx.x, nt = blockIdx.y, mat = blockIdx.z;
  const float* U  = (mat == 0) ? Uz  : (mat == 1 ? Ur  : Uh);
  const float* Wb = (mat == 0) ? Wzb : (mat == 1 ? Wrb : Whb);
  unsigned short* uo = (mat == 0) ? ubz : (mat == 1 ? ubr : ubh);

  __shared__ short lA[4096];   // [64][64] bf16, 128B rows, XOR-swizzled
  __shared__ short lB[4096];

  const int tid = threadIdx.x;
  const int wave = tid >> 6, lane = tid & 63;
  const int fl = lane & 15, kseg = lane >> 4;

  f32x4 acc[4];
  #pragma unroll
  for (int n = 0; n < 4; ++n) acc[n] = f32x4{0.f, 0.f, 0.f, 0.f};

  const float* xb = x + (size_t)mt * 64 * 512;
  const float* Ub = U + (size_t)nt * 64 * 512;

  for (int kt = 0; kt < 8; ++kt) {
    __syncthreads();
    #pragma unroll
    for (int c = 0; c < 2; ++c) {
      const int chunk = tid + 256 * c;       // 0..511
      const int row = chunk >> 3, kc = chunk & 7;
      const int lb = row * 128 + ((kc * 16) ^ ((row & 7) << 4));
      {
        const float* g = xb + (size_t)row * 512 + kt * 64 + kc * 8;
        fvec4 a0 = *(const fvec4*)g, a1 = *(const fvec4*)(g + 4);
        bf16x8 p;
        p[0] = (short)f2bf(a0[0]); p[1] = (short)f2bf(a0[1]);
        p[2] = (short)f2bf(a0[2]); p[3] = (short)f2bf(a0[3]);
        p[4] = (short)f2bf(a1[0]); p[5] = (short)f2bf(a1[1]);
        p[6] = (short)f2bf(a1[2]); p[7] = (short)f2bf(a1[3]);
        *(bf16x8*)((char*)lA + lb) = p;
      }
      {
        const float* g = Ub + (size_t)row * 512 + kt * 64 + kc * 8;
        fvec4 a0 = *(const fvec4*)g, a1 = *(const fvec4*)(g + 4);
        bf16x8 p;
        p[0] = (short)f2bf(a0[0]); p[1] = (short)f2bf(a0[1]);
        p[2] = (short)f2bf(a0[2]); p[3] = (short)f2bf(a0[3]);
        p[4] = (short)f2bf(a1[0]); p[5] = (short)f2bf(a1[1]);
        p[6] = (short)f2bf(a1[2]); p[7] = (short)f2bf(a1[3]);
        *(bf16x8*)((char*)lB + lb) = p;
      }
    }
    __syncthreads();
    #pragma unroll
    for (int kk = 0; kk < 2; ++kk) {
      const int ar = wave * 16 + fl;
      bf16x8 af = *(const bf16x8*)((char*)lA + ar * 128 +
                    ((kk * 64 + kseg * 16) ^ ((ar & 7) << 4)));
      #pragma unroll
      for (int n = 0; n < 4; ++n) {
        const int br = n * 16 + fl;
        bf16x8 bfr = *(const bf16x8*)((char*)lB + br * 128 +
                      ((kk * 64 + kseg * 16) ^ ((br & 7) << 4)));
        acc[n] = __builtin_amdgcn_mfma_f32_16x16x32_bf16(af, bfr, acc[n], 0, 0, 0);
      }
    }
  }

  // ---- BN epilogue: exact batch stats (all 64 rows), from fp32 accs ----
  float sn[4], qn[4];
  #pragma unroll
  for (int n = 0; n < 4; ++n) {
    sn[n] = acc[n][0] + acc[n][1] + acc[n][2] + acc[n][3];
    qn[n] = acc[n][0]*acc[n][0] + acc[n][1]*acc[n][1]
          + acc[n][2]*acc[n][2] + acc[n][3]*acc[n][3];
    sn[n] += __shfl_xor(sn[n], 16); qn[n] += __shfl_xor(qn[n], 16);
    sn[n] += __shfl_xor(sn[n], 32); qn[n] += __shfl_xor(qn[n], 32);
  }
  __syncthreads();                       // all MFMA LDS reads done; reuse lA/lB
  float* sArr = (float*)lA;              // [wave*64 + n*16 + fl]
  float* qArr = (float*)lB;
  if (kseg == 0) {
    #pragma unroll
    for (int n = 0; n < 4; ++n) {
      sArr[wave * 64 + n * 16 + fl] = sn[n];
      qArr[wave * 64 + n * 16 + fl] = qn[n];
    }
  }
  __syncthreads();

  const int c0 = nt * 64;
  const int b0 = wave * 16 + kseg * 4;     // batch base for this thread
  #pragma unroll
  for (int n = 0; n < 4; ++n) {
    const int idx = n * 16 + fl;
    const float s = sArr[idx] + sArr[64+idx] + sArr[128+idx] + sArr[192+idx];
    const float q = qArr[idx] + qArr[64+idx] + qArr[128+idx] + qArr[192+idx];
    const float mu = s * 0.015625f;
    const float rs = rsqrtf(q * 0.015625f - mu * mu + 1e-5f);
    const int col = c0 + idx;
    const float gb  = gamma[col] * rs;
    const float ofs = beta[col] + Wb[col] - gb * mu;   // fold W bias here
    s16x4 pk;
    #pragma unroll
    for (int i = 0; i < 4; ++i)
      pk[i] = (short)f2h(gb * acc[n][i] + ofs);
    // transposed layout: [t][col][batch]
    *(s16x4*)(uo + ((size_t)mt * 512 + col) * 64 + b0) = pk;
  }
}

// ---------------- phase 2: persistent GRU scan ----------------
__global__ __launch_bounds__(256) void gru_scan(
    const float* __restrict__ h0,
    const float* __restrict__ Wz, const float* __restrict__ Wr,
    const float* __restrict__ Wh,
    const unsigned short* __restrict__ ubz, const unsigned short* __restrict__ ubr,
    const unsigned short* __restrict__ ubh,
    unsigned short* __restrict__ hbuf, unsigned short* __restrict__ rhbuf,
    unsigned int* __restrict__ flags, float* __restrict__ out)
{
  const int wg = blockIdx.x;           // owns cols [wg*16, wg*16+16)
  const int tid = threadIdx.x;
  const int wave = tid >> 6, lane = tid & 63;
  const int fl = lane & 15, kseg = lane >> 4;
  const int col = wg * 16 + fl;        // this lane's output column
  const int row0 = wave * 16 + kseg * 4;   // first of 4 C-rows (batch)
  const int hrow = wave * 16 + fl;         // A-frag row (batch)

  // W slices, bf16, [mat][16 rows][512 k], 1KB rows, XOR-swizzled
  __shared__ short lW[24576];

  for (int c = tid; c < 3072; c += 256) {        // 8-elem chunks
    const int m = c >> 10, rem = c & 1023;
    const int r = rem >> 6, kc = rem & 63;
    const float* W = (m == 0) ? Wz : (m == 1 ? Wr : Wh);
    const float* g = W + (size_t)(wg * 16 + r) * 512 + kc * 8;
    bf16x8 p;
    #pragma unroll
    for (int j = 0; j < 8; ++j) p[j] = (short)f2bf(g[j]);
    *(bf16x8*)((char*)lW + m * 16384 + r * 1024 + ((kc * 16) ^ ((r & 7) << 4))) = p;
  }

  // barrier helpers: per-WG epoch flag, one 128B line each.
  // arrive: (all waves synced) tid0 release-stores the epoch.
  // wait: lanes 0..31 of EVERY wave poll the 32 flags in parallel.
  auto wait_ev = [&](unsigned int ev) {
    if (lane < NWG) {
      while (__hip_atomic_load(&flags[lane << 5], __ATOMIC_RELAXED,
                               __HIP_MEMORY_SCOPE_AGENT) < ev) {}
    }
    __builtin_amdgcn_fence(__ATOMIC_ACQUIRE, "agent");
  };

  // own h columns, fp32, never leave registers
  float hown[4];
  #pragma unroll
  for (int i = 0; i < 4; ++i) {
    const float v = h0[(size_t)(row0 + i) * 512 + col];
    hown[i] = v;
    hbuf[(size_t)(row0 + i) * 512 + col] = f2bf(v);
  }
  __syncthreads();
  if (tid == 0)
    __hip_atomic_store(&flags[wg << 5], 1u, __ATOMIC_RELEASE, __HIP_MEMORY_SCOPE_AGENT);

  // prefetch BN-ed u for t=0 (biases folded; layout [t][col][batch])
  float uzv[4], urv[4], uhv[4];
  {
    const size_t ub = ((size_t)col) * 64 + row0;
    s16x4 az = *(const s16x4*)(ubz + ub);
    s16x4 ar = *(const s16x4*)(ubr + ub);
    s16x4 ah = *(const s16x4*)(ubh + ub);
    #pragma unroll
    for (int i = 0; i < 4; ++i) {
      uzv[i] = h2f((unsigned short)az[i]);
      urv[i] = h2f((unsigned short)ar[i]);
      uhv[i] = h2f((unsigned short)ah[i]);
    }
  }

  for (int t = 0; t < 512; ++t) {
    // ---- wait: h (version t) visible everywhere
    wait_ev(2 * t + 1);

    // ---- phase 1: z, r gates for our 16 columns
    bf16x8 af[16];
    #pragma unroll
    for (int kk = 0; kk < 16; ++kk)
      af[kk] = *(const bf16x8*)((const char*)hbuf + hrow * 1024 + kk * 64 + kseg * 16);

    f32x4 zacc = f32x4{0.f,0.f,0.f,0.f}, racc = f32x4{0.f,0.f,0.f,0.f};
    #pragma unroll
    for (int kk = 0; kk < 16; ++kk) {
      const int wof = (kk * 64 + kseg * 16) ^ ((fl & 7) << 4);
      bf16x8 b0 = *(const bf16x8*)((const char*)lW + fl * 1024 + wof);
      bf16x8 b1 = *(const bf16x8*)((const char*)lW + 16384 + fl * 1024 + wof);
      zacc = __builtin_amdgcn_mfma_f32_16x16x32_bf16(af[kk], b0, zacc, 0, 0, 0);
      racc = __builtin_amdgcn_mfma_f32_16x16x32_bf16(af[kk], b1, racc, 0, 0, 0);
    }

    float z4[4], r4[4];
    #pragma unroll
    for (int i = 0; i < 4; ++i) {
      z4[i] = sigmoidf_(zacc[i] + uzv[i]);
      r4[i] = sigmoidf_(racc[i] + urv[i]);
    }

    // rh slice (own cols, fp32 h from regs)
    #pragma unroll
    for (int i = 0; i < 4; ++i)
      rhbuf[(size_t)(row0 + i) * 512 + col] = f2bf(r4[i] * hown[i]);

    // ---- mid barrier: rh complete
    __syncthreads();
    if (tid == 0)
      __hip_atomic_store(&flags[wg << 5], 2u * t + 2u, __ATOMIC_RELEASE,
                         __HIP_MEMORY_SCOPE_AGENT);
    wait_ev(2 * t + 2);

    // ---- phase 2: candidate state
    #pragma unroll
    for (int kk = 0; kk < 16; ++kk)
      af[kk] = *(const bf16x8*)((const char*)rhbuf + hrow * 1024 + kk * 64 + kseg * 16);

    f32x4 hacc = f32x4{0.f,0.f,0.f,0.f};
    #pragma unroll
    for (int kk = 0; kk < 16; ++kk) {
      const int wof = (kk * 64 + kseg * 16) ^ ((fl & 7) << 4);
      bf16x8 b2 = *(const bf16x8*)((const char*)lW + 32768 + fl * 1024 + wof);
      hacc = __builtin_amdgcn_mfma_f32_16x16x32_bf16(af[kk], b2, hacc, 0, 0, 0);
    }

    float hn[4];
    #pragma unroll
    for (int i = 0; i < 4; ++i) {
      const float nb = tanhf_(hacc[i] + uhv[i]);
      hn[i] = (1.f - z4[i]) * hown[i] + z4[i] * nb;
      hown[i] = hn[i];
    }
    #pragma unroll
    for (int i = 0; i < 4; ++i)
      hbuf[(size_t)(row0 + i) * 512 + col] = f2bf(hn[i]);

    // ---- end barrier arrival: h (version t+1) complete
    __syncthreads();
    if (tid == 0)
      __hip_atomic_store(&flags[wg << 5], 2u * t + 3u, __ATOMIC_RELEASE,
                         __HIP_MEMORY_SCOPE_AGENT);

    // prefetch next step's u during the (upcoming) barrier wait
    if (t + 1 < 512) {
      const size_t ub = ((size_t)(t + 1) * 512 + col) * 64 + row0;
      s16x4 az = *(const s16x4*)(ubz + ub);
      s16x4 ar = *(const s16x4*)(ubr + ub);
      s16x4 ah = *(const s16x4*)(ubh + ub);
      #pragma unroll
      for (int i = 0; i < 4; ++i) {
        uzv[i] = h2f((unsigned short)az[i]);
        urv[i] = h2f((unsigned short)ar[i]);
        uhv[i] = h2f((unsigned short)ah[i]);
      }
    }
    // outputs (fire-and-forget, after arrival): both copies are hs[t]
    {
      const size_t tb = (size_t)t * 64 * 512;
      #pragma unroll
      for (int i = 0; i < 4; ++i) {
        const size_t o = tb + (size_t)(row0 + i) * 512 + col;
        const float v = hn[i];
        out[o] = v;
        out[16777216 + o] = v;
      }
    }
  }
}

extern "C" void kernel_launch(void* const* d_in, const int* in_sizes, int n_in,
                              void* d_out, int out_size, void* d_ws, size_t ws_size,
                              hipStream_t stream) {
  (void)in_sizes; (void)n_in; (void)out_size; (void)ws_size;
  const float* x   = (const float*)d_in[0];
  const float* h0  = (const float*)d_in[1];
  const float* Wz  = (const float*)d_in[2];
  const float* Wzb = (const float*)d_in[3];
  const float* Uz  = (const float*)d_in[4];
  const float* Wr  = (const float*)d_in[6];
  const float* Wrb = (const float*)d_in[7];
  const float* Ur  = (const float*)d_in[8];
  const float* Wh  = (const float*)d_in[10];
  const float* Whb = (const float*)d_in[11];
  const float* Uh  = (const float*)d_in[12];
  const float* gam = (const float*)d_in[14];
  const float* bet = (const float*)d_in[15];
  float* out = (float*)d_out;

  char* ws = (char*)d_ws;
  // layout: [0,8KB) per-WG epoch flags (128B stride) | hbuf 64KB | rhbuf 64KB
  //         | [256KB) ub_z, ub_r, ub_h (fp16 BN-ed + bias, [t][col][b], 32MB)
  unsigned int*   flags = (unsigned int*)(ws);
  unsigned short* hbuf  = (unsigned short*)(ws + 8192);
  unsigned short* rhbuf = (unsigned short*)(ws + 8192 + 65536);
  unsigned short* uzb   = (unsigned short*)(ws + 262144);
  unsigned short* urb   = (unsigned short*)(ws + 262144 + 33554432);
  unsigned short* uhb   = (unsigned short*)(ws + 262144 + 2ll * 33554432);

  hipMemsetAsync(flags, 0, 8192, stream);   // epoch flags -> 0

  dim3 gp(512, 8, 3);
  proj_gemm<<<gp, 256, 0, stream>>>(x, Uz, Ur, Uh, Wzb, Wrb, Whb,
                                    gam, bet, uzb, urb, uhb);
  gru_scan<<<dim3(NWG), 256, 0, stream>>>(h0, Wz, Wr, Wh, uzb, urb, uhb,
                                          hbuf, rhbuf, flags, out);
}